// Round 1
// 1465.622 us; speedup vs baseline: 1.0246x; 1.0246x over previous
//
#include <hip/hip_runtime.h>
#include <hip/hip_fp16.h>

typedef _Float16 f16;
typedef f16 f16x8 __attribute__((ext_vector_type(8)));
typedef float f32x4 __attribute__((ext_vector_type(4)));

#define NPIX 16384
#define DDIM 256
#define KCB  8192
#define KCAT 768
#define LOG2E 1.44269504088896340736f

// ---- async global->LDS (16B per lane, lane-contiguous LDS dest) ----
__device__ __forceinline__ void lds_async16(const void* g, void* l) {
    __builtin_amdgcn_global_load_lds(
        (const __attribute__((address_space(1))) unsigned int*)g,
        (__attribute__((address_space(3))) unsigned int*)l,
        16, 0, 0);
}

#define VM2  asm volatile("s_waitcnt vmcnt(2)" ::: "memory")
#define VM0  asm volatile("s_waitcnt vmcnt(0)" ::: "memory")
#define LG0  asm volatile("s_waitcnt lgkmcnt(0)" ::: "memory")
#define BAR  { __builtin_amdgcn_sched_barrier(0); __builtin_amdgcn_s_barrier(); __builtin_amdgcn_sched_barrier(0); }

// ---- init scratch (ws re-poisoned 0xAA before every call) ----
__global__ void init_k(float* gsum, unsigned long long* gmin) {
    int i = blockIdx.x * 256 + threadIdx.x;
    if (i < NPIX) { gsum[i] = 0.f; gmin[i] = ~0ULL; }
}

// ---- split x into fp16 hi/lo, packed [xh | xl | xh] per row (K=768) ----
// x pre-scaled by 2*log2(e): MFMA then yields log2-domain logits directly,
// and the epilogue uses native exp2 with no extra muls. argmin ordering is
// invariant under the positive scale.
__global__ void prep_x(const float* __restrict__ x, f16* __restrict__ Acat) {
    int p = blockIdx.x, d = threadIdx.x;
    float v = x[p * DDIM + d] * (2.0f * LOG2E);
    f16 h = (f16)v;
    f16 lo = (f16)(v - (float)h);
    Acat[p * KCAT + d]        = h;
    Acat[p * KCAT + 256 + d]  = lo;
    Acat[p * KCAT + 512 + d]  = h;
}

// ---- split codebook, packed [ch | ch | cl]; c2 = ||c||^2 * log2(e) ----
__global__ void prep_c(const float* __restrict__ cb, f16* __restrict__ Bcat,
                       float* __restrict__ c2) {
    int k = blockIdx.x, d = threadIdx.x;
    float v = cb[k * DDIM + d];
    f16 h = (f16)v;
    f16 lo = (f16)(v - (float)h);
    Bcat[k * KCAT + d]       = h;
    Bcat[k * KCAT + 256 + d] = h;
    Bcat[k * KCAT + 512 + d] = lo;
    float v2 = v * v;
    #pragma unroll
    for (int m = 32; m; m >>= 1) v2 += __shfl_xor(v2, m);
    __shared__ float ws4[4];
    if ((threadIdx.x & 63) == 0) ws4[threadIdx.x >> 6] = v2;
    __syncthreads();
    if (threadIdx.x == 0) c2[k] = (ws4[0] + ws4[1] + ws4[2] + ws4[3]) * LOG2E;
}

// ---- transpose ch into chT[256][8192] f16 for gemm2 B-operand ----
__global__ void transpose_c(const f16* __restrict__ Bcat, f16* __restrict__ chT) {
    __shared__ f16 tile[64][68];
    int k0 = blockIdx.x * 64, d0 = blockIdx.y * 64;
    #pragma unroll
    for (int i = 0; i < 16; ++i) {
        int idx = i * 256 + threadIdx.x;
        int kl = idx >> 6, dl = idx & 63;
        tile[kl][dl] = Bcat[(k0 + kl) * KCAT + d0 + dl];
    }
    __syncthreads();
    #pragma unroll
    for (int i = 0; i < 16; ++i) {
        int idx = i * 256 + threadIdx.x;
        int dl = idx >> 6, kl = idx & 63;
        chT[(size_t)(d0 + dl) * KCB + k0 + kl] = tile[kl][dl];
    }
}

// ---- GEMM1: u = exp2(acc - c2' + noise*log2e) + row-sum + argmin ----
// 128x128 tile, BK=32, 4 waves. v2: double-buffered LDS (distinct objects),
// stage(t+1) issued before compute(t), ONE barrier per K-step (was 2), and
// XOR granule swizzle so ds_read_b128 fragments are bank-conflict-free.
// Swizzle: LDS 16B-granule (row r, g) holds source granule g ^ (r&3) ^ ((r>>2)&3)
// (64B row stride -> this spreads the 16 fr-lanes over all 32 banks).
__global__ __launch_bounds__(256) void gemm1(
    const f16* __restrict__ A, const f16* __restrict__ B,
    const float* __restrict__ c2, const float* __restrict__ noise,
    float* __restrict__ U, float* __restrict__ gsum,
    unsigned long long* __restrict__ gmin)
{
    __shared__ f16 As0[128 * 32];
    __shared__ f16 As1[128 * 32];
    __shared__ f16 Bs0[128 * 32];
    __shared__ f16 Bs1[128 * 32];
    __shared__ float lsum[128];
    __shared__ unsigned long long lmin[128];

    const int tid = threadIdx.x;
    const int lane = tid & 63, wid = tid >> 6;
    const int bm = blockIdx.y, bn = blockIdx.x;
    const int wm = (wid & 1) * 64, wn = (wid >> 1) * 64;
    const int fr = lane & 15;
    const int q4 = lane >> 4;                            // k-granule 0..3
    // swizzled k-offset (halves); row&3 == fr&3, (row>>2)&3 == (fr>>2)&3
    const int kg = ((q4 ^ (fr & 3) ^ ((fr >> 2) & 3)) << 3);

    if (tid < 128) { lsum[tid] = 0.f; lmin[tid] = ~0ULL; }

    const f32x4 z = {0.f, 0.f, 0.f, 0.f};
    f32x4 acc[4][4];
    #pragma unroll
    for (int i = 0; i < 4; ++i)
        #pragma unroll
        for (int j = 0; j < 4; ++j) acc[i][j] = z;

    // staging: thread t owns 16B chunk q -> (row = q/64, granule = (q>>4)&3),
    // LDS dest stays linear (lane*16 rule), global source is inverse-swizzled.
    const int q = tid * 16;
    const int sr = q >> 6;
    const int sg = ((((q >> 4) & 3) ^ (sr & 3) ^ ((sr >> 2) & 3)) << 3);
    const f16* Ab = A + (size_t)(bm * 128 + sr) * KCAT + sg;
    const f16* Bb = B + (size_t)(bn * 128 + sr) * KCAT + sg;

    auto stage = [&](int t, char* asd, char* bsd) {
        const int k0 = t * 32;
        lds_async16(Ab + k0,            asd + q);
        lds_async16(Ab + 64 * KCAT + k0, asd + q + 4096);
        lds_async16(Bb + k0,            bsd + q);
        lds_async16(Bb + 64 * KCAT + k0, bsd + q + 4096);
    };
    auto compute = [&](const f16* as, const f16* bs) {
        f16x8 a[4], b[4];
        #pragma unroll
        for (int i = 0; i < 4; ++i)
            a[i] = *(const f16x8*)(as + (wm + i * 16 + fr) * 32 + kg);
        #pragma unroll
        for (int j = 0; j < 4; ++j)
            b[j] = *(const f16x8*)(bs + (wn + j * 16 + fr) * 32 + kg);
        #pragma unroll
        for (int i = 0; i < 4; ++i)
            #pragma unroll
            for (int j = 0; j < 4; ++j)
                acc[i][j] = __builtin_amdgcn_mfma_f32_16x16x32_f16(a[i], b[j], acc[i][j], 0, 0, 0);
    };

    stage(0, (char*)As0, (char*)Bs0);
    __syncthreads();
    for (int t = 0; t < 24; t += 2) {
        stage(t + 1, (char*)As1, (char*)Bs1);   // prefetch next while computing
        compute(As0, Bs0);
        __syncthreads();                         // drains prefetch (covered by mfma)
        if (t + 2 < 24) stage(t + 2, (char*)As0, (char*)Bs0);
        compute(As1, Bs1);
        __syncthreads();
    }

    // epilogue: C/D map col=lane&15, row=(lane>>4)*4+reg
    const int cbase = bn * 128 + wn + fr;
    float cc[4];
    #pragma unroll
    for (int j = 0; j < 4; ++j) cc[j] = c2[cbase + j * 16];
    const int rq = q4 * 4;

    #pragma unroll
    for (int i = 0; i < 4; ++i) {
        const int rowl = wm + i * 16 + rq;
        const int rowg = bm * 128 + rowl;
        // batch the 16 noise loads for this i-slice (issue together, then use)
        float nz[4][4];
        #pragma unroll
        for (int r = 0; r < 4; ++r) {
            const float* np_ = noise + (size_t)(rowg + r) * KCB + cbase;
            #pragma unroll
            for (int j = 0; j < 4; ++j) nz[r][j] = np_[j * 16];
        }
        #pragma unroll
        for (int r = 0; r < 4; ++r) {
            float* up = U + (size_t)(rowg + r) * KCB + cbase;
            float sum4 = 0.f;
            unsigned long long pk = ~0ULL;
            #pragma unroll
            for (int j = 0; j < 4; ++j) {
                const float xc2 = acc[i][j][r];              // log2e*2*x.c
                const float tt = xc2 - cc[j] + nz[r][j] * LOG2E;
                const float u = exp2f(tt);
                up[j * 16] = u;
                sum4 += u;
                const float s = cc[j] - xc2;                 // monotone in dist
                unsigned int bb = __float_as_uint(s);
                bb = (bb & 0x80000000u) ? ~bb : (bb | 0x80000000u);
                unsigned long long p =
                    ((unsigned long long)bb << 32) | (unsigned int)(cbase + j * 16);
                pk = p < pk ? p : pk;
            }
            #pragma unroll
            for (int m = 1; m <= 8; m <<= 1) {
                sum4 += __shfl_xor(sum4, m);
                unsigned long long op = __shfl_xor(pk, m);
                pk = op < pk ? op : pk;
            }
            if (fr == 0) {
                atomicAdd(&lsum[rowl + r], sum4);
                atomicMin(&lmin[rowl + r], pk);
            }
        }
    }
    __syncthreads();
    if (tid < 128) {
        atomicAdd(&gsum[bm * 128 + tid], lsum[tid]);
        atomicMin(&gmin[bm * 128 + tid], lmin[tid]);
    }
}

// ---- GEMM2: normalize u -> E (in place), quantized = E @ ch, write indices ----
// BM=32 rows, BN=256 (full D), BK=64. v2: raw-barrier pipeline, 1 barrier per
// K-step (was 2), counted vmcnt, per-wave-PRIVATE B staging (each wave only
// consumes its own 64 D-rows -> no cross-wave hazard on Bsw), double-buffered
// As (distinct objects), one-body-deep register prefetch of the U stream.
// Bsw XOR swizzle (128B rows): LDS granule (r,g) holds source granule g^(r&7).
//
// vmcnt queue model (per lane, oldest->newest), steady state at body-k entry:
//   [Estore(k) x2, Bstage(k) x8, Uload(k+1) x2]  -> wait vmcnt(2): B(k) ready,
//   U(k+1) stays in flight a full body (consumed next scalestore).
__global__ __launch_bounds__(256) void gemm2(
    float* __restrict__ U, const f16* __restrict__ chT,
    const float* __restrict__ gsum, const unsigned long long* __restrict__ gmin,
    float* __restrict__ Q, float* __restrict__ IDX)
{
    __shared__ f16 As0[32 * 72];          // padded stride 72 halves
    __shared__ f16 As1[32 * 72];
    __shared__ f16 Bsw[4 * 4096];         // 4 waves x (64 D-rows x 64 halves)
    __shared__ float invl[32];

    const int tid = threadIdx.x, lane = tid & 63, wid = tid >> 6;
    const int r0 = blockIdx.x * 32;
    if (tid < 32) {
        invl[tid] = 1.0f / gsum[r0 + tid];
        IDX[r0 + tid] = (float)(unsigned int)(gmin[r0 + tid] & 0xFFFFFFFFull);
    }

    const int arow = tid >> 3;
    const int akc = (tid & 7) * 8;
    const int fr = lane & 15, q4 = lane >> 4, fkh = q4 * 8;
    // B-read swizzled half-offsets for ks=0/1: g' = (ks*4 + q4) ^ (fr&7)
    const int g0 = ((q4 ^ (fr & 7)) << 3);
    const int g1 = (((q4 ^ 4) ^ (fr & 7)) << 3);
    f16* const myB = Bsw + wid * 4096;
    const int d0 = wid * 64;
    // stage mapping: chunk c, lane l -> n=c*64+l -> (row=n>>3, g=n&7);
    // inverse-swizzled source granule = g ^ (row&7) = (l&7) ^ (l>>3)
    const int brow = lane >> 3;
    const int bgs = (((lane & 7) ^ brow) << 3);
    const f16* const bsrc = chT + (size_t)(d0 + brow) * KCB + bgs;

    auto stageB = [&](int k) {
        const int k0 = k * 64;
        #pragma unroll
        for (int c = 0; c < 8; ++c)
            lds_async16(bsrc + (size_t)(c * 8) * KCB + k0,
                        (char*)myB + c * 1024 + lane * 16);
    };

    float* const urow = U + (size_t)(r0 + arow) * KCB + akc;

    const f32x4 z = {0.f, 0.f, 0.f, 0.f};
    f32x4 acc[2][4];
    #pragma unroll
    for (int i = 0; i < 2; ++i)
        #pragma unroll
        for (int j = 0; j < 4; ++j) acc[i][j] = z;

    float il;
    auto scalestore = [&](const float4& u0v, const float4& u1v, int kidx, f16* asd) {
        float e0 = u0v.x * il, e1 = u0v.y * il, e2 = u0v.z * il, e3 = u0v.w * il;
        float e4 = u1v.x * il, e5 = u1v.y * il, e6 = u1v.z * il, e7 = u1v.w * il;
        *(float4*)(urow + (size_t)kidx * 64)     = make_float4(e0, e1, e2, e3);
        *(float4*)(urow + (size_t)kidx * 64 + 4) = make_float4(e4, e5, e6, e7);
        f16x8 h;
        h[0] = (f16)e0; h[1] = (f16)e1; h[2] = (f16)e2; h[3] = (f16)e3;
        h[4] = (f16)e4; h[5] = (f16)e5; h[6] = (f16)e6; h[7] = (f16)e7;
        *(f16x8*)(asd + arow * 72 + akc) = h;
    };
    auto domfma = [&](const f16* as_) {
        #pragma unroll
        for (int ks = 0; ks < 2; ++ks) {
            const int go = ks ? g1 : g0;
            f16x8 a0 = *(const f16x8*)(as_ + fr * 72 + ks * 32 + fkh);
            f16x8 a1 = *(const f16x8*)(as_ + (16 + fr) * 72 + ks * 32 + fkh);
            #pragma unroll
            for (int j = 0; j < 4; ++j) {
                f16x8 bj = *(const f16x8*)(myB + (j * 16 + fr) * 64 + go);
                acc[0][j] = __builtin_amdgcn_mfma_f32_16x16x32_f16(a0, bj, acc[0][j], 0, 0, 0);
                acc[1][j] = __builtin_amdgcn_mfma_f32_16x16x32_f16(a1, bj, acc[1][j], 0, 0, 0);
            }
        }
    };

    // ---- prologue ----
    float4 ua0, ua1, ub0, ub1;
    ua0 = *(const float4*)(urow);        ua1 = *(const float4*)(urow + 4);     // u(0)
    ub0 = *(const float4*)(urow + 64);   ub1 = *(const float4*)(urow + 68);    // u(1)
    stageB(0);
    __syncthreads();                     // invl visible; drains prologue vmem
    il = invl[arow];
    scalestore(ua0, ua1, 0, As0);        // E(0), As0 <- u(0)
    LG0; BAR;

    for (int kk = 0; kk < 128; kk += 2) {
        // ---- body k = kk (even): uses As0 + B(kk) ----
        VM2;                              // B(kk) complete; keeps U(kk+1) in flight
        domfma(As0);
        scalestore(ub0, ub1, kk + 1, As1);   // E(kk+1), As1 <- u(kk+1)
        stageB(kk + 1);
        if (kk + 2 < 128) {
            ua0 = *(const float4*)(urow + (size_t)(kk + 2) * 64);
            ua1 = *(const float4*)(urow + (size_t)(kk + 2) * 64 + 4);
        }
        LG0; BAR;
        // ---- body k = kk+1 (odd): uses As1 + B(kk+1) ----
        if (kk == 126) { VM0; } else { VM2; }   // last tile: B(127) is newest
        domfma(As1);
        if (kk + 2 < 128) {
            scalestore(ua0, ua1, kk + 2, As0);
            stageB(kk + 2);
            ub0 = *(const float4*)(urow + (size_t)(kk + 3) * 64);
            ub1 = *(const float4*)(urow + (size_t)(kk + 3) * 64 + 4);
        }
        LG0; BAR;
    }

    const int rq = q4 * 4;
    #pragma unroll
    for (int i = 0; i < 2; ++i)
        #pragma unroll
        for (int j = 0; j < 4; ++j) {
            const int col = wid * 64 + j * 16 + fr;
            #pragma unroll
            for (int r = 0; r < 4; ++r) {
                const int row = r0 + i * 16 + rq + r;
                Q[row * DDIM + col] = acc[i][j][r];
            }
        }
}

extern "C" void kernel_launch(void* const* d_in, const int* in_sizes, int n_in,
                              void* d_out, int out_size, void* d_ws, size_t ws_size,
                              hipStream_t stream) {
    const float* x     = (const float*)d_in[0];
    const float* cb    = (const float*)d_in[1];
    const float* noise = (const float*)d_in[2];

    float* Q   = (float*)d_out;                       // [16384,256]
    float* E   = Q + 4194304;                         // [16384,8192]
    float* IDX = Q + 138412032;                       // [16384]

    char* ws = (char*)d_ws;
    f16* Acat = (f16*)ws;                             // 25,165,824 B
    f16* Bcat = (f16*)(ws + 25165824);                // 12,582,912 B
    f16* chT  = (f16*)(ws + 37748736);                //  4,194,304 B
    float* c2 = (float*)(ws + 41943040);              //     32,768 B
    float* gsum = (float*)(ws + 41975808);            //     65,536 B
    unsigned long long* gmin =
        (unsigned long long*)(ws + 42041344);         //    131,072 B

    init_k<<<64, 256, 0, stream>>>(gsum, gmin);
    prep_x<<<NPIX, 256, 0, stream>>>(x, Acat);
    prep_c<<<KCB, 256, 0, stream>>>(cb, Bcat, c2);
    transpose_c<<<dim3(128, 4), 256, 0, stream>>>(Bcat, chT);
    gemm1<<<dim3(64, 128), 256, 0, stream>>>(Acat, Bcat, c2, noise, E, gsum, gmin);
    gemm2<<<512, 256, 0, stream>>>(E, chT, gsum, gmin, Q, IDX);
}